// Round 11
// baseline (789.421 us; speedup 1.0000x reference)
//
#include <hip/hip_runtime.h>
#include <hip/hip_bf16.h>

// ---------------------------------------------------------------------------
// EnhancedTernaryLinear: out = (x @ W^T) * scale + bias
// M=8192, N=4096, K=4096. x->bf16, W(ternary)->bf16, then 256x256 MFMA GEMM.
// R11: R10 (zero-VALU saddr staging) with the global_load_lds offset bug
// fixed: the builtin's imm offset applies to BOTH global and LDS addresses
// (LLVM IntrinsicsAMDGPU.td), so ALL calls now use offset 0; the (T+2)*BK
// B-slab gets its own uniform pointer Bs2, and tile-1 prologue staging uses
// explicit +BK pointers.
// ---------------------------------------------------------------------------

#define M_DIM 8192
#define N_DIM 4096
#define K_DIM 4096
#define BK 64
#define NT (K_DIM / BK)   // 64 K-tiles

typedef __attribute__((ext_vector_type(8))) short bf16x8;
typedef __attribute__((ext_vector_type(4))) float f32x4;

__device__ __forceinline__ unsigned short f2bf(float f) {
  unsigned int u = __float_as_uint(f);
  unsigned int r = (u + 0x7FFFu + ((u >> 16) & 1u)) >> 16;
  return (unsigned short)r;
}

// global->LDS async copy, 16B/lane, offset ALWAYS 0 (imm applies to BOTH
// global and LDS addresses -- R10 post-mortem)
#define ASYNC16(g, l)                                                   \
  __builtin_amdgcn_global_load_lds(                                     \
      (const __attribute__((address_space(1))) void*)(g),               \
      (__attribute__((address_space(3))) void*)(l), 16, 0, 0)

// ---------------- conversion kernels ----------------

__global__ void cvt_x_kernel(const float* __restrict__ x,
                             unsigned short* __restrict__ xb, long n) {
  long i0 = ((long)blockIdx.x * blockDim.x + threadIdx.x) * 8;
  long stride = (long)gridDim.x * blockDim.x * 8;
  for (long i = i0; i < n; i += stride) {
    float4 v0 = *(const float4*)(x + i);
    float4 v1 = *(const float4*)(x + i + 4);
    bf16x8 o;
    o[0] = (short)f2bf(v0.x); o[1] = (short)f2bf(v0.y);
    o[2] = (short)f2bf(v0.z); o[3] = (short)f2bf(v0.w);
    o[4] = (short)f2bf(v1.x); o[5] = (short)f2bf(v1.y);
    o[6] = (short)f2bf(v1.z); o[7] = (short)f2bf(v1.w);
    *(bf16x8*)(xb + i) = o;
  }
}

__device__ __forceinline__ unsigned short i2bf(int v) {
  return v == 0 ? (unsigned short)0
                : (v > 0 ? (unsigned short)0x3F80 : (unsigned short)0xBF80);
}

__global__ void cvt_w_kernel(const int* __restrict__ w,
                             unsigned short* __restrict__ wb, long n) {
  long i0 = ((long)blockIdx.x * blockDim.x + threadIdx.x) * 8;
  long stride = (long)gridDim.x * blockDim.x * 8;
  for (long i = i0; i < n; i += stride) {
    int4 a = *(const int4*)(w + i);
    int4 b = *(const int4*)(w + i + 4);
    bf16x8 o;
    o[0] = (short)i2bf(a.x); o[1] = (short)i2bf(a.y);
    o[2] = (short)i2bf(a.z); o[3] = (short)i2bf(a.w);
    o[4] = (short)i2bf(b.x); o[5] = (short)i2bf(b.y);
    o[6] = (short)i2bf(b.z); o[7] = (short)i2bf(b.w);
    *(bf16x8*)(wb + i) = o;
  }
}

// ---------------- 256x256 GEMM, R5 pipeline, saddr staging ----------------
// 512 threads = 8 waves (2 wr x 4 wc). Wave tile 128x64 = 8x4 frags 16x16x32.
// LDS (shorts), 128 KiB: A(b,mh) = b*32768 + mh*8192 (128 rows x 64 el);
//   B(b,nh) = b*32768 + 16384 + nh*8192.
// Swizzle: stored_byte = logical ^ ((row&7)<<4); staged via inverse-swizzled
// GLOBAL source + linear LDS dest (rule 21); read with swizzled base.
// Staging (zero per-tile VALU): per-thread 32-bit element row-offsets
// roA*/roB* + uniform pointers As=(T+2)*BK, Bs=(T+1)*BK, Bs2=(T+2)*BK,
// advanced by += BK per tile (SALU only).
// Phases per tile T (buf b), R5 waits verbatim:
//   q0: rd bF1 [4]; stage B-nh0(T+1)->b^1; LGKM(4);  MFMA(aFx,bF0)
//   q1: rd aFy [8]; stage A-mh0(T+2)->b;   LGKM(8);  MFMA(aFx,bF1)
//   q2:             stage B-nh1(T+2)->b;   LGKM(0);  MFMA(aFy,bF1); VMW(4|0)
//   q3: rd aFx',bFn [12]; stage A-mh1(T+2)->b; LGKM(12); MFMA(aFy,bF0)
// bF0/bFn parity-swap across the 2-tile unroll (no copies).

#define DSR(dst, base, OFF)                                     \
  asm volatile("ds_read_b128 %0, %1 offset:" OFF                \
               : "=v"(dst) : "v"(base))
#define LGKM(N)                                                 \
  asm volatile("s_waitcnt lgkmcnt(" #N ")" ::: "memory");       \
  __builtin_amdgcn_sched_barrier(0)
#define VMW(N) asm volatile("s_waitcnt vmcnt(" #N ")" ::: "memory")

__device__ __forceinline__ void rd_a(unsigned b0, bf16x8 aF[4][2]) {
  unsigned b1 = b0 ^ 64;
  DSR(aF[0][0], b0, "0");    DSR(aF[0][1], b1, "0");
  DSR(aF[1][0], b0, "2048"); DSR(aF[1][1], b1, "2048");
  DSR(aF[2][0], b0, "4096"); DSR(aF[2][1], b1, "4096");
  DSR(aF[3][0], b0, "6144"); DSR(aF[3][1], b1, "6144");
}
__device__ __forceinline__ void rd_b(unsigned b0, bf16x8 bF[2][2]) {
  unsigned b1 = b0 ^ 64;
  DSR(bF[0][0], b0, "0");    DSR(bF[0][1], b1, "0");
  DSR(bF[1][0], b0, "2048"); DSR(bF[1][1], b1, "2048");
}

#define MFMA16(AF, BF, MH, NH)                                                 \
  do {                                                                         \
    __builtin_amdgcn_s_setprio(1);                                             \
    _Pragma("unroll") for (int kk = 0; kk < 2; ++kk)                           \
    _Pragma("unroll") for (int mi = 0; mi < 4; ++mi)                           \
    _Pragma("unroll") for (int ni = 0; ni < 2; ++ni)                           \
      acc[(MH)*4 + mi][(NH)*2 + ni] = __builtin_amdgcn_mfma_f32_16x16x32_bf16( \
          AF[mi][kk], BF[ni][kk], acc[(MH)*4 + mi][(NH)*2 + ni], 0, 0, 0);     \
    __builtin_amdgcn_s_setprio(0);                                             \
    __builtin_amdgcn_sched_barrier(0);                                         \
  } while (0)

// Stage macros: uniform base + per-thread 32-bit rowoff (saddr form).
#define ST_A0(DST)                                               \
  do { ASYNC16(As + roA00, lds + (DST) + t * 8);                 \
       ASYNC16(As + roA01, lds + (DST) + 4096 + t * 8); } while (0)
#define ST_A1(DST)                                               \
  do { ASYNC16(As + roA10, lds + (DST) + t * 8);                 \
       ASYNC16(As + roA11, lds + (DST) + 4096 + t * 8); } while (0)
#define ST_B0(DST)                                               \
  do { ASYNC16(Bs + roB00, lds + (DST) + t * 8);                 \
       ASYNC16(Bs + roB01, lds + (DST) + 4096 + t * 8); } while (0)
#define ST_B1(DST)  /* (T+2)*BK slab via Bs2 */                  \
  do { ASYNC16(Bs2 + roB10, lds + (DST) + t * 8);                \
       ASYNC16(Bs2 + roB11, lds + (DST) + 4096 + t * 8); } while (0)

// One K-tile. BFC/BFN: current/next-tile B-nh0 frags (parity swap).
#define TILE(TT, BFC, BFN, RA1, RAn, RB1, RBn, D_B0, D_A0, D_B1, D_A1)         \
  do {                                                                         \
    const int T_ = (TT);                                                       \
    /* q0 */                                                                   \
    rd_b(rcB + (RB1), bF1);                                                    \
    if (T_ + 1 < NT) ST_B0(D_B0);                                              \
    LGKM(4);                                                                   \
    MFMA16(aFx, BFC, 0, 0);                                                    \
    __builtin_amdgcn_s_barrier();                                              \
    /* q1 */                                                                   \
    rd_a(rcA + (RA1), aFy);                                                    \
    if (T_ + 2 < NT) ST_A0(D_A0);                                              \
    LGKM(8);                                                                   \
    MFMA16(aFx, bF1, 0, 1);                                                    \
    __builtin_amdgcn_s_barrier();                                              \
    /* q2 */                                                                   \
    if (T_ + 2 < NT) ST_B1(D_B1);                                              \
    LGKM(0);                                                                   \
    MFMA16(aFy, bF1, 1, 1);                                                    \
    if (T_ < NT - 2) { VMW(4); }                                               \
    else if (T_ == NT - 2) { VMW(0); }                                         \
    __builtin_amdgcn_s_barrier();                                              \
    /* q3 */                                                                   \
    if (T_ + 1 < NT) {                                                         \
      rd_a(rcA + (RAn), aFx);                                                  \
      rd_b(rcB + (RBn), BFN);                                                  \
      if (T_ + 2 < NT) ST_A1(D_A1);                                            \
      LGKM(12);                                                                \
      MFMA16(aFy, BFC, 1, 0);                                                  \
    } else {                                                                   \
      LGKM(0);                                                                 \
      MFMA16(aFy, BFC, 1, 0);                                                  \
    }                                                                          \
    __builtin_amdgcn_s_barrier();                                              \
    As += BK; Bs += BK; Bs2 += BK;                                             \
  } while (0)

__global__ void __launch_bounds__(512, 2)
gemm_bt_kernel(const unsigned short* __restrict__ A,  // bf16 [M][K]
               const unsigned short* __restrict__ B,  // bf16 [N][K]
               const float* __restrict__ scale, const float* __restrict__ bias,
               float* __restrict__ C) {
  __shared__ unsigned short lds[65536];  // 128 KiB

  const int t = threadIdx.x;
  const int bid = blockIdx.x;
  const int swz = (bid & 7) * 64 + (bid >> 3);  // 512 wgs, 64/XCD (bijective)
  const int bm = swz >> 4;  // 32 M-tiles
  const int bn = swz & 15;  // 16 N-tiles
  const int brow = bm * 256, bcol = bn * 256;

  const int wid = t >> 6, lane = t & 63;
  const int wr = wid >> 2, wc = wid & 3;
  const int fr = lane & 15, fq = lane >> 4;

  // ---- per-thread staging row offsets (elements; constant all kernel) ----
  const int colb = (t & 7) * 16;                  // logical byte col
  const int ssw = ((t >> 3) & 7) << 4;            // row-swizzle bits
  const int scol = (colb ^ ssw) >> 1;             // inverse-swz source col
  const int rho0 = t >> 3, rho1 = 64 + (t >> 3);
  // A region row -> global row: r = (rho>>6)*128 + mh*64 + (rho&63)
  const unsigned roA00 = (unsigned)((((rho0 >> 6) << 7) + (rho0 & 63)) * K_DIM + scol);
  const unsigned roA01 = (unsigned)((((rho1 >> 6) << 7) + (rho1 & 63)) * K_DIM + scol);
  const unsigned roA10 = roA00 + 64u * K_DIM;
  const unsigned roA11 = roA01 + 64u * K_DIM;
  // B region row -> global col: c = (rho>>5)*64 + nh*32 + (rho&31)
  const unsigned roB00 = (unsigned)((((rho0 >> 5) << 6) + (rho0 & 31)) * K_DIM + scol);
  const unsigned roB01 = (unsigned)((((rho1 >> 5) << 6) + (rho1 & 31)) * K_DIM + scol);
  const unsigned roB10 = roB00 + 32u * K_DIM;
  const unsigned roB11 = roB01 + 32u * K_DIM;

  const unsigned short* Ablk = A + (size_t)brow * K_DIM;
  const unsigned short* Bblk = B + (size_t)bcol * K_DIM;

  // ds_read bases (swizzle folded); buf/region via literal byte adds
  const unsigned ldsb = (unsigned)(unsigned long long)&lds[0];
  const unsigned cswz = ((unsigned)(fq * 16)) ^ ((unsigned)((fr & 7) << 4));
  const unsigned rcA = ldsb + (unsigned)((wr * 64 + fr) * 128) + cswz;
  const unsigned rcB = ldsb + (unsigned)((wc * 32 + fr) * 128) + cswz;

  f32x4 acc[8][4] = {};
  bf16x8 aFx[4][2], aFy[4][2], bF0[2][2], bF1[2][2], bFn[2][2];

  // ---- prologue: tile0 (4 halves) + tile1 {A-mh0, B-nh1, A-mh1} ----
  const unsigned short* A1 = Ablk + BK;   // tile1 k-slab
  const unsigned short* B1 = Bblk + BK;
  ASYNC16(Ablk + roA00, lds + 0 + t * 8);            // t0 A-mh0
  ASYNC16(Ablk + roA01, lds + 4096 + t * 8);
  ASYNC16(Bblk + roB10, lds + 24576 + t * 8);        // t0 B-nh1
  ASYNC16(Bblk + roB11, lds + 28672 + t * 8);
  ASYNC16(Ablk + roA10, lds + 8192 + t * 8);         // t0 A-mh1
  ASYNC16(Ablk + roA11, lds + 12288 + t * 8);
  ASYNC16(Bblk + roB00, lds + 16384 + t * 8);        // t0 B-nh0
  ASYNC16(Bblk + roB01, lds + 20480 + t * 8);
  ASYNC16(A1 + roA00, lds + 32768 + t * 8);          // t1 A-mh0
  ASYNC16(A1 + roA01, lds + 36864 + t * 8);
  ASYNC16(B1 + roB10, lds + 57344 + t * 8);          // t1 B-nh1
  ASYNC16(B1 + roB11, lds + 61440 + t * 8);
  ASYNC16(A1 + roA10, lds + 40960 + t * 8);          // t1 A-mh1
  ASYNC16(A1 + roA11, lds + 45056 + t * 8);
  VMW(6);  // tile0's 8 stage-loads landed
  __builtin_amdgcn_s_barrier();
  rd_a(rcA + 0u, aFx);        // tile0 mh0
  rd_b(rcB + 32768u, bF0);    // tile0 nh0 (12 lgkm outstanding entering loop)

  // uniform stage pointers: As=(T+2)*BK, Bs=(T+1)*BK, Bs2=(T+2)*BK
  const unsigned short* As = Ablk + 2 * BK;
  const unsigned short* Bs = Bblk + BK;
  const unsigned short* Bs2 = Bblk + 2 * BK;

  for (int T = 0; T < NT; T += 2) {
    // tile T (buf0): consume bF0, preload bFn
    TILE(T, bF0, bFn,
         16384u /*b0 mh1*/, 65536u /*b1 mh0*/,
         49152u /*b0 nh1*/, 98304u /*b1 nh0*/,
         49152 /*B(1,0)*/, 0 /*A(0,0)*/, 24576 /*B(0,1)*/, 8192 /*A(0,1)*/);
    // tile T+1 (buf1): consume bFn, preload bF0
    TILE(T + 1, bFn, bF0,
         81920u /*b1 mh1*/, 0u /*b0 mh0*/,
         114688u /*b1 nh1*/, 32768u /*b0 nh0*/,
         16384 /*B(0,0)*/, 32768 /*A(1,0)*/, 57344 /*B(1,1)*/, 40960 /*A(1,1)*/);
  }

  // ---- epilogue: scale/bias, C/D layout col=lane&15, row=(lane>>4)*4+j ----
#pragma unroll
  for (int n = 0; n < 4; ++n) {
    const int gc = bcol + wc * 64 + n * 16 + fr;
    const float s = scale[gc];
    const float bo = bias[gc];
#pragma unroll
    for (int m = 0; m < 8; ++m) {
      const int gr = brow + wr * 128 + m * 16 + fq * 4;
#pragma unroll
      for (int j = 0; j < 4; ++j)
        C[(size_t)(gr + j) * N_DIM + gc] = acc[m][n][j] * s + bo;
    }
  }
}

// ---------------- naive fallback (only if ws too small) ----------------

__global__ void naive_kernel(const float* __restrict__ x, const int* __restrict__ w,
                             const float* __restrict__ sc, const float* __restrict__ bi,
                             float* __restrict__ out) {
  size_t idx = (size_t)blockIdx.x * blockDim.x + threadIdx.x;
  int m = (int)(idx >> 12);
  int n = (int)(idx & 4095);
  const float* xr = x + (size_t)m * K_DIM;
  const int* wr = w + (size_t)n * K_DIM;
  float acc = 0.f;
  for (int k = 0; k < K_DIM; ++k) acc = fmaf(xr[k], (float)wr[k], acc);
  out[idx] = acc * sc[n] + bi[n];
}

extern "C" void kernel_launch(void* const* d_in, const int* in_sizes, int n_in,
                              void* d_out, int out_size, void* d_ws, size_t ws_size,
                              hipStream_t stream) {
  const float* x = (const float*)d_in[0];
  const int* w = (const int*)d_in[1];
  const float* scale = (const float*)d_in[2];
  const float* bias = (const float*)d_in[3];
  float* out = (float*)d_out;

  const long nx = (long)M_DIM * K_DIM;
  const long nw = (long)N_DIM * K_DIM;
  const size_t need = (size_t)nx * 2 + (size_t)nw * 2;  // 96 MiB

  if (ws_size >= need) {
    unsigned short* xb = (unsigned short*)d_ws;
    unsigned short* wb = xb + nx;
    cvt_x_kernel<<<2048, 256, 0, stream>>>(x, xb, nx);
    cvt_w_kernel<<<2048, 256, 0, stream>>>(w, wb, nw);
    gemm_bt_kernel<<<512, 512, 0, stream>>>(xb, wb, scale, bias, out);
  } else {
    naive_kernel<<<((long)M_DIM * N_DIM) / 256, 256, 0, stream>>>(x, w, scale, bias, out);
  }
}

// Round 12
// 261.525 us; speedup vs baseline: 3.0185x; 3.0185x over previous
//
#include <hip/hip_runtime.h>
#include <hip/hip_bf16.h>

// ---------------------------------------------------------------------------
// EnhancedTernaryLinear: out = (x @ W^T) * scale + bias
// M=8192, N=4096, K=4096. x->bf16, W(ternary)->bf16, then 256x256 MFMA GEMM.
// R12 = R5 (session champion, 226us gemm / 261us total) restored verbatim:
// 4-phase read-ahead pipeline, counted lgkmcnt + sched_barrier, one barrier
// per phase, XOR-swizzled LDS (0 conflicts), XCD-swizzled grid.
// ---------------------------------------------------------------------------

#define M_DIM 8192
#define N_DIM 4096
#define K_DIM 4096
#define BK 64
#define NT (K_DIM / BK)   // 64 K-tiles

typedef __attribute__((ext_vector_type(8))) short bf16x8;
typedef __attribute__((ext_vector_type(4))) float f32x4;

__device__ __forceinline__ unsigned short f2bf(float f) {
  unsigned int u = __float_as_uint(f);
  unsigned int r = (u + 0x7FFFu + ((u >> 16) & 1u)) >> 16;
  return (unsigned short)r;
}

__device__ __forceinline__ void async16(const void* g, void* l) {
  __builtin_amdgcn_global_load_lds(
      (const __attribute__((address_space(1))) void*)g,
      (__attribute__((address_space(3))) void*)l, 16, 0, 0);
}

// ---------------- conversion kernels ----------------

__global__ void cvt_x_kernel(const float* __restrict__ x,
                             unsigned short* __restrict__ xb, long n) {
  long i0 = ((long)blockIdx.x * blockDim.x + threadIdx.x) * 8;
  long stride = (long)gridDim.x * blockDim.x * 8;
  for (long i = i0; i < n; i += stride) {
    float4 v0 = *(const float4*)(x + i);
    float4 v1 = *(const float4*)(x + i + 4);
    bf16x8 o;
    o[0] = (short)f2bf(v0.x); o[1] = (short)f2bf(v0.y);
    o[2] = (short)f2bf(v0.z); o[3] = (short)f2bf(v0.w);
    o[4] = (short)f2bf(v1.x); o[5] = (short)f2bf(v1.y);
    o[6] = (short)f2bf(v1.z); o[7] = (short)f2bf(v1.w);
    *(bf16x8*)(xb + i) = o;
  }
}

__device__ __forceinline__ unsigned short i2bf(int v) {
  return v == 0 ? (unsigned short)0
                : (v > 0 ? (unsigned short)0x3F80 : (unsigned short)0xBF80);
}

__global__ void cvt_w_kernel(const int* __restrict__ w,
                             unsigned short* __restrict__ wb, long n) {
  long i0 = ((long)blockIdx.x * blockDim.x + threadIdx.x) * 8;
  long stride = (long)gridDim.x * blockDim.x * 8;
  for (long i = i0; i < n; i += stride) {
    int4 a = *(const int4*)(w + i);
    int4 b = *(const int4*)(w + i + 4);
    bf16x8 o;
    o[0] = (short)i2bf(a.x); o[1] = (short)i2bf(a.y);
    o[2] = (short)i2bf(a.z); o[3] = (short)i2bf(a.w);
    o[4] = (short)i2bf(b.x); o[5] = (short)i2bf(b.y);
    o[6] = (short)i2bf(b.z); o[7] = (short)i2bf(b.w);
    *(bf16x8*)(wb + i) = o;
  }
}

// ---------------- 256x256 GEMM, 4 phases/K-tile, read-ahead 1 phase -------
// 512 threads = 8 waves (2 wr x 4 wc). Per-wave output 128x64 = 8x4 frags.
// LDS regions (ushort offsets), 128 KiB:
//   A (buf,mh): buf*32768 + mh*8192        (128 rows x 64 cols bf16)
//   B (buf,nh): buf*32768 + 16384 + nh*8192
// Swizzle: LDS[rho][bytecol ^ ((rho&7)<<4)]; staged via inverse-swizzled
// GLOBAL source + linear LDS dest, read with swizzled offset. 0 conflicts.
//
// MFMA usage: q0:(aFx,bF0) q1:(aFx,bF1) q2:(aFy,bF1) q3:(aFy,bF0).
// Reads issued (consumed NEXT phase):  q0: bF1(T) [4]; q1: aFy(T) [8];
//   q2: none; q3: aFx(T+1)+bF0n(T+1) [12].
// Waits before MFMA: q0 lgkm(4), q1 lgkm(8), q2 lgkm(0), q3 lgkm(12).
// Stages (global_load_lds): q0 -> B-nh0(T+1); q1 -> A-mh0(T+2);
//   q2 -> B-nh1(T+2); q3 -> A-mh1(T+2). vmcnt(4) at q2-end retires all of
//   tile T+1's staging (incl. q0(T)'s B-nh0) before q3's reads of it.
// One s_barrier per phase (end). Every stage targets a region whose last
// reads drained at the preceding phase's counted lgkm wait -> WAR safe.

#define AOFF(b, mh) ((b)*32768 + (mh)*8192)
#define BOFF(b, nh) ((b)*32768 + 16384 + (nh)*8192)

__device__ __forceinline__ void stage_A_half(const unsigned short* __restrict__ A,
                                             int grow0, int ktE, int mh,
                                             unsigned short* lds_region, int t) {
  const int colb = (t & 7) * 16;
  const int swz = ((t >> 3) & 7) << 4;
  const int scol = (colb ^ swz) >> 1;  // element offset in row
#pragma unroll
  for (int rr = 0; rr < 2; ++rr) {
    int rho = rr * 64 + (t >> 3);
    int r = ((rho >> 6) << 7) + mh * 64 + (rho & 63);
    async16(A + (size_t)(grow0 + r) * K_DIM + ktE + scol,
            lds_region + rr * 4096 + t * 8);
  }
}

__device__ __forceinline__ void stage_B_half(const unsigned short* __restrict__ B,
                                             int gcol0, int ktE, int nh,
                                             unsigned short* lds_region, int t) {
  const int colb = (t & 7) * 16;
  const int swz = ((t >> 3) & 7) << 4;
  const int scol = (colb ^ swz) >> 1;
#pragma unroll
  for (int rr = 0; rr < 2; ++rr) {
    int rho = rr * 64 + (t >> 3);
    int c = ((rho >> 5) << 6) + nh * 32 + (rho & 31);
    async16(B + (size_t)(gcol0 + c) * K_DIM + ktE + scol,
            lds_region + rr * 4096 + t * 8);
  }
}

// Inline-asm ds_read_b128: guaranteed width (lgkm counts depend on it).
#define DSR(dst, base, OFF)                                     \
  asm volatile("ds_read_b128 %0, %1 offset:" OFF                \
               : "=v"(dst) : "v"(base))

__device__ __forceinline__ void rd_a(unsigned b0, bf16x8 aF[4][2]) {
  unsigned b1 = b0 ^ 64;  // kk=1 (byte col ^64, swizzle-compatible)
  DSR(aF[0][0], b0, "0");    DSR(aF[0][1], b1, "0");
  DSR(aF[1][0], b0, "2048"); DSR(aF[1][1], b1, "2048");
  DSR(aF[2][0], b0, "4096"); DSR(aF[2][1], b1, "4096");
  DSR(aF[3][0], b0, "6144"); DSR(aF[3][1], b1, "6144");
}
__device__ __forceinline__ void rd_b(unsigned b0, bf16x8 bF[2][2]) {
  unsigned b1 = b0 ^ 64;
  DSR(bF[0][0], b0, "0");    DSR(bF[0][1], b1, "0");
  DSR(bF[1][0], b0, "2048"); DSR(bF[1][1], b1, "2048");
}

#define LGKM(N)                                                  \
  asm volatile("s_waitcnt lgkmcnt(" #N ")" ::: "memory");        \
  __builtin_amdgcn_sched_barrier(0)
#define VMW(N) asm volatile("s_waitcnt vmcnt(" #N ")" ::: "memory")

#define MFMA16(AF, BF, MH, NH)                                                 \
  do {                                                                         \
    __builtin_amdgcn_s_setprio(1);                                             \
    _Pragma("unroll") for (int kk = 0; kk < 2; ++kk)                           \
    _Pragma("unroll") for (int mi = 0; mi < 4; ++mi)                           \
    _Pragma("unroll") for (int ni = 0; ni < 2; ++ni)                           \
      acc[(MH)*4 + mi][(NH)*2 + ni] = __builtin_amdgcn_mfma_f32_16x16x32_bf16( \
          AF[mi][kk], BF[ni][kk], acc[(MH)*4 + mi][(NH)*2 + ni], 0, 0, 0);     \
    __builtin_amdgcn_s_setprio(0);                                             \
    __builtin_amdgcn_sched_barrier(0);                                         \
  } while (0)

__global__ void __launch_bounds__(512, 2)
gemm_bt_kernel(const unsigned short* __restrict__ A,  // bf16 [M][K]
               const unsigned short* __restrict__ B,  // bf16 [N][K]
               const float* __restrict__ scale, const float* __restrict__ bias,
               float* __restrict__ C) {
  __shared__ unsigned short lds[65536];  // 128 KiB

  const int t = threadIdx.x;
  const int bid = blockIdx.x;
  const int swz = (bid & 7) * 64 + (bid >> 3);  // 512 wgs, 64/XCD (bijective)
  const int bm = swz >> 4;  // 32 M-tiles
  const int bn = swz & 15;  // 16 N-tiles
  const int brow = bm * 256, bcol = bn * 256;

  const int wid = t >> 6, lane = t & 63;
  const int wr = wid >> 2, wc = wid & 3;
  const int fr = lane & 15, fq = lane >> 4;

  // ds_read base addresses (LDS byte offsets; low 32 bits of generic ptr)
  const unsigned ldsb = (unsigned)(unsigned long long)&lds[0];
  const unsigned swzcol = ((unsigned)(fq * 16)) ^ ((unsigned)((fr & 7) << 4));
  const unsigned rcA = ldsb + (unsigned)((wr * 64 + fr) * 128) + swzcol;
  const unsigned rcB = ldsb + (unsigned)((wc * 32 + fr) * 128) + swzcol;

  f32x4 acc[8][4] = {};
  bf16x8 aFx[4][2], aFy[4][2], bF0[2][2], bF1[2][2], bF0n[2][2];

  // ---- prologue: tile0 (4 halves) + tile1 {A-mh0, B-nh1, A-mh1} ----
  stage_A_half(A, brow, 0, 0, lds + AOFF(0, 0), t);
  stage_B_half(B, bcol, 0, 1, lds + BOFF(0, 1), t);
  stage_A_half(A, brow, 0, 1, lds + AOFF(0, 1), t);
  stage_B_half(B, bcol, 0, 0, lds + BOFF(0, 0), t);
  stage_A_half(A, brow, BK, 0, lds + AOFF(1, 0), t);
  stage_B_half(B, bcol, BK, 1, lds + BOFF(1, 1), t);
  stage_A_half(A, brow, BK, 1, lds + AOFF(1, 1), t);
  VMW(6);  // tile0's 8 stage-loads landed
  __builtin_amdgcn_s_barrier();
  // q3(-1) role: read tile0's aFx + bF0 (12 outstanding entering the loop)
  rd_a(rcA + ((unsigned)AOFF(0, 0) << 1), aFx);
  rd_b(rcB + ((unsigned)BOFF(0, 0) << 1), bF0);

  for (int T = 0; T < NT; ++T) {
    const int b = T & 1;

    // -- q0: MFMA(mh0,nh0); issue bF1(T) reads; stage B-nh0(T+1)
    rd_b(rcB + ((unsigned)BOFF(b, 1) << 1), bF1);
    if (T + 1 < NT) stage_B_half(B, bcol, (T + 1) * BK, 0, lds + BOFF(b ^ 1, 0), t);
    LGKM(4);  // aFx + bF0 (issued last phase) drained; own 4 may pend
    MFMA16(aFx, bF0, 0, 0);
    __builtin_amdgcn_s_barrier();

    // -- q1: MFMA(mh0,nh1); issue aFy(T) reads; stage A-mh0(T+2)
    rd_a(rcA + ((unsigned)AOFF(b, 1) << 1), aFy);
    if (T + 2 < NT) stage_A_half(A, brow, (T + 2) * BK, 0, lds + AOFF(b, 0), t);
    LGKM(8);  // bF1 drained; own 8 may pend
    MFMA16(aFx, bF1, 0, 1);
    __builtin_amdgcn_s_barrier();

    // -- q2: MFMA(mh1,nh1); no reads; stage B-nh1(T+2); vmcnt once/tile
    if (T + 2 < NT) stage_B_half(B, bcol, (T + 2) * BK, 1, lds + BOFF(b, 1), t);
    LGKM(0);  // aFy drained (issued a full phase ago -> ~free)
    MFMA16(aFy, bF1, 1, 1);
    if (T < NT - 2)
      VMW(4);  // retires all tile-T+1 staging (outstanding = q1,q2 stages)
    else if (T == NT - 2)
      VMW(0);  // final drain
    __builtin_amdgcn_s_barrier();

    // -- q3: MFMA(mh1,nh0); issue aFx'+bF0n(T+1) reads; stage A-mh1(T+2)
    if (T + 1 < NT) {
      rd_a(rcA + ((unsigned)AOFF(b ^ 1, 0) << 1), aFx);
      rd_b(rcB + ((unsigned)BOFF(b ^ 1, 0) << 1), bF0n);
      if (T + 2 < NT) stage_A_half(A, brow, (T + 2) * BK, 1, lds + AOFF(b, 1), t);
      LGKM(12);  // nothing older outstanding; own 12 may pend
      MFMA16(aFy, bF0, 1, 0);  // uses OLD bF0 (pre-reload SSA values)
#pragma unroll
      for (int ni = 0; ni < 2; ++ni)
#pragma unroll
        for (int kk = 0; kk < 2; ++kk) bF0[ni][kk] = bF0n[ni][kk];
    } else {
      LGKM(0);
      MFMA16(aFy, bF0, 1, 0);
    }
    __builtin_amdgcn_s_barrier();
  }

  // ---- epilogue: scale/bias, C/D layout col=lane&15, row=(lane>>4)*4+j ----
#pragma unroll
  for (int n = 0; n < 4; ++n) {
    const int gc = bcol + wc * 64 + n * 16 + fr;
    const float s = scale[gc];
    const float bo = bias[gc];
#pragma unroll
    for (int m = 0; m < 8; ++m) {
      const int gr = brow + wr * 128 + m * 16 + fq * 4;
#pragma unroll
      for (int j = 0; j < 4; ++j)
        C[(size_t)(gr + j) * N_DIM + gc] = acc[m][n][j] * s + bo;
    }
  }
}

// ---------------- naive fallback (only if ws too small) ----------------

__global__ void naive_kernel(const float* __restrict__ x, const int* __restrict__ w,
                             const float* __restrict__ sc, const float* __restrict__ bi,
                             float* __restrict__ out) {
  size_t idx = (size_t)blockIdx.x * blockDim.x + threadIdx.x;
  int m = (int)(idx >> 12);
  int n = (int)(idx & 4095);
  const float* xr = x + (size_t)m * K_DIM;
  const int* wr = w + (size_t)n * K_DIM;
  float acc = 0.f;
  for (int k = 0; k < K_DIM; ++k) acc = fmaf(xr[k], (float)wr[k], acc);
  out[idx] = acc * sc[n] + bi[n];
}

extern "C" void kernel_launch(void* const* d_in, const int* in_sizes, int n_in,
                              void* d_out, int out_size, void* d_ws, size_t ws_size,
                              hipStream_t stream) {
  const float* x = (const float*)d_in[0];
  const int* w = (const int*)d_in[1];
  const float* scale = (const float*)d_in[2];
  const float* bias = (const float*)d_in[3];
  float* out = (float*)d_out;

  const long nx = (long)M_DIM * K_DIM;
  const long nw = (long)N_DIM * K_DIM;
  const size_t need = (size_t)nx * 2 + (size_t)nw * 2;  // 96 MiB

  if (ws_size >= need) {
    unsigned short* xb = (unsigned short*)d_ws;
    unsigned short* wb = xb + nx;
    cvt_x_kernel<<<2048, 256, 0, stream>>>(x, xb, nx);
    cvt_w_kernel<<<2048, 256, 0, stream>>>(w, wb, nw);
    gemm_bt_kernel<<<512, 512, 0, stream>>>(xb, wb, scale, bias, out);
  } else {
    naive_kernel<<<((long)M_DIM * N_DIM) / 256, 256, 0, stream>>>(x, w, scale, bias, out);
  }
}

// Round 13
// 259.855 us; speedup vs baseline: 3.0379x; 1.0064x over previous
//
#include <hip/hip_runtime.h>
#include <hip/hip_bf16.h>

// ---------------------------------------------------------------------------
// EnhancedTernaryLinear: out = (x @ W^T) * scale + bias
// M=8192, N=4096, K=4096. x->bf16, W(ternary)->bf16 in ONE fused kernel,
// then the R5/R12 champion 256x256 MFMA GEMM (4-phase read-ahead pipeline,
// counted lgkmcnt + sched_barrier, one barrier per phase, XOR-swizzled LDS,
// XCD-swizzled grid). R13 = champion + fused conversion prologue.
// ---------------------------------------------------------------------------

#define M_DIM 8192
#define N_DIM 4096
#define K_DIM 4096
#define BK 64
#define NT (K_DIM / BK)   // 64 K-tiles

typedef __attribute__((ext_vector_type(8))) short bf16x8;
typedef __attribute__((ext_vector_type(4))) float f32x4;

__device__ __forceinline__ unsigned short f2bf(float f) {
  unsigned int u = __float_as_uint(f);
  unsigned int r = (u + 0x7FFFu + ((u >> 16) & 1u)) >> 16;
  return (unsigned short)r;
}

__device__ __forceinline__ unsigned short i2bf(int v) {
  return v == 0 ? (unsigned short)0
                : (v > 0 ? (unsigned short)0x3F80 : (unsigned short)0xBF80);
}

__device__ __forceinline__ void async16(const void* g, void* l) {
  __builtin_amdgcn_global_load_lds(
      (const __attribute__((address_space(1))) void*)g,
      (__attribute__((address_space(3))) void*)l, 16, 0, 0);
}

// ---------------- fused conversion kernel (one launch) ----------------

__global__ void cvt_fused_kernel(const float* __restrict__ x,
                                 const int* __restrict__ w,
                                 unsigned short* __restrict__ xb,
                                 unsigned short* __restrict__ wb,
                                 long nx, long nw) {
  long i0 = ((long)blockIdx.x * blockDim.x + threadIdx.x) * 8;
  long stride = (long)gridDim.x * blockDim.x * 8;
  for (long i = i0; i < nx; i += stride) {
    float4 v0 = *(const float4*)(x + i);
    float4 v1 = *(const float4*)(x + i + 4);
    bf16x8 o;
    o[0] = (short)f2bf(v0.x); o[1] = (short)f2bf(v0.y);
    o[2] = (short)f2bf(v0.z); o[3] = (short)f2bf(v0.w);
    o[4] = (short)f2bf(v1.x); o[5] = (short)f2bf(v1.y);
    o[6] = (short)f2bf(v1.z); o[7] = (short)f2bf(v1.w);
    *(bf16x8*)(xb + i) = o;
  }
  for (long i = i0; i < nw; i += stride) {
    int4 a = *(const int4*)(w + i);
    int4 b = *(const int4*)(w + i + 4);
    bf16x8 o;
    o[0] = (short)i2bf(a.x); o[1] = (short)i2bf(a.y);
    o[2] = (short)i2bf(a.z); o[3] = (short)i2bf(a.w);
    o[4] = (short)i2bf(b.x); o[5] = (short)i2bf(b.y);
    o[6] = (short)i2bf(b.z); o[7] = (short)i2bf(b.w);
    *(bf16x8*)(wb + i) = o;
  }
}

// ---------------- 256x256 GEMM, 4 phases/K-tile, read-ahead 1 phase -------
// 512 threads = 8 waves (2 wr x 4 wc). Per-wave output 128x64 = 8x4 frags.
// LDS regions (ushort offsets), 128 KiB:
//   A (buf,mh): buf*32768 + mh*8192        (128 rows x 64 cols bf16)
//   B (buf,nh): buf*32768 + 16384 + nh*8192
// Swizzle: LDS[rho][bytecol ^ ((rho&7)<<4)]; staged via inverse-swizzled
// GLOBAL source + linear LDS dest, read with swizzled offset. 0 conflicts.
//
// MFMA usage: q0:(aFx,bF0) q1:(aFx,bF1) q2:(aFy,bF1) q3:(aFy,bF0).
// Reads issued (consumed NEXT phase):  q0: bF1(T) [4]; q1: aFy(T) [8];
//   q2: none; q3: aFx(T+1)+bF0n(T+1) [12].
// Waits before MFMA: q0 lgkm(4), q1 lgkm(8), q2 lgkm(0), q3 lgkm(12).
// Stages (global_load_lds): q0 -> B-nh0(T+1); q1 -> A-mh0(T+2);
//   q2 -> B-nh1(T+2); q3 -> A-mh1(T+2). vmcnt(4) at q2-end retires all of
//   tile T+1's staging (incl. q0(T)'s B-nh0) before q3's reads of it.
// One s_barrier per phase (end). Every stage targets a region whose last
// reads drained at the preceding phase's counted lgkm wait -> WAR safe.

#define AOFF(b, mh) ((b)*32768 + (mh)*8192)
#define BOFF(b, nh) ((b)*32768 + 16384 + (nh)*8192)

__device__ __forceinline__ void stage_A_half(const unsigned short* __restrict__ A,
                                             int grow0, int ktE, int mh,
                                             unsigned short* lds_region, int t) {
  const int colb = (t & 7) * 16;
  const int swz = ((t >> 3) & 7) << 4;
  const int scol = (colb ^ swz) >> 1;  // element offset in row
#pragma unroll
  for (int rr = 0; rr < 2; ++rr) {
    int rho = rr * 64 + (t >> 3);
    int r = ((rho >> 6) << 7) + mh * 64 + (rho & 63);
    async16(A + (size_t)(grow0 + r) * K_DIM + ktE + scol,
            lds_region + rr * 4096 + t * 8);
  }
}

__device__ __forceinline__ void stage_B_half(const unsigned short* __restrict__ B,
                                             int gcol0, int ktE, int nh,
                                             unsigned short* lds_region, int t) {
  const int colb = (t & 7) * 16;
  const int swz = ((t >> 3) & 7) << 4;
  const int scol = (colb ^ swz) >> 1;
#pragma unroll
  for (int rr = 0; rr < 2; ++rr) {
    int rho = rr * 64 + (t >> 3);
    int c = ((rho >> 5) << 6) + nh * 32 + (rho & 31);
    async16(B + (size_t)(gcol0 + c) * K_DIM + ktE + scol,
            lds_region + rr * 4096 + t * 8);
  }
}

// Inline-asm ds_read_b128: guaranteed width (lgkm counts depend on it).
#define DSR(dst, base, OFF)                                     \
  asm volatile("ds_read_b128 %0, %1 offset:" OFF                \
               : "=v"(dst) : "v"(base))

__device__ __forceinline__ void rd_a(unsigned b0, bf16x8 aF[4][2]) {
  unsigned b1 = b0 ^ 64;  // kk=1 (byte col ^64, swizzle-compatible)
  DSR(aF[0][0], b0, "0");    DSR(aF[0][1], b1, "0");
  DSR(aF[1][0], b0, "2048"); DSR(aF[1][1], b1, "2048");
  DSR(aF[2][0], b0, "4096"); DSR(aF[2][1], b1, "4096");
  DSR(aF[3][0], b0, "6144"); DSR(aF[3][1], b1, "6144");
}
__device__ __forceinline__ void rd_b(unsigned b0, bf16x8 bF[2][2]) {
  unsigned b1 = b0 ^ 64;
  DSR(bF[0][0], b0, "0");    DSR(bF[0][1], b1, "0");
  DSR(bF[1][0], b0, "2048"); DSR(bF[1][1], b1, "2048");
}

#define LGKM(N)                                                  \
  asm volatile("s_waitcnt lgkmcnt(" #N ")" ::: "memory");        \
  __builtin_amdgcn_sched_barrier(0)
#define VMW(N) asm volatile("s_waitcnt vmcnt(" #N ")" ::: "memory")

#define MFMA16(AF, BF, MH, NH)                                                 \
  do {                                                                         \
    __builtin_amdgcn_s_setprio(1);                                             \
    _Pragma("unroll") for (int kk = 0; kk < 2; ++kk)                           \
    _Pragma("unroll") for (int mi = 0; mi < 4; ++mi)                           \
    _Pragma("unroll") for (int ni = 0; ni < 2; ++ni)                           \
      acc[(MH)*4 + mi][(NH)*2 + ni] = __builtin_amdgcn_mfma_f32_16x16x32_bf16( \
          AF[mi][kk], BF[ni][kk], acc[(MH)*4 + mi][(NH)*2 + ni], 0, 0, 0);     \
    __builtin_amdgcn_s_setprio(0);                                             \
    __builtin_amdgcn_sched_barrier(0);                                         \
  } while (0)

__global__ void __launch_bounds__(512, 2)
gemm_bt_kernel(const unsigned short* __restrict__ A,  // bf16 [M][K]
               const unsigned short* __restrict__ B,  // bf16 [N][K]
               const float* __restrict__ scale, const float* __restrict__ bias,
               float* __restrict__ C) {
  __shared__ unsigned short lds[65536];  // 128 KiB

  const int t = threadIdx.x;
  const int bid = blockIdx.x;
  const int swz = (bid & 7) * 64 + (bid >> 3);  // 512 wgs, 64/XCD (bijective)
  const int bm = swz >> 4;  // 32 M-tiles
  const int bn = swz & 15;  // 16 N-tiles
  const int brow = bm * 256, bcol = bn * 256;

  const int wid = t >> 6, lane = t & 63;
  const int wr = wid >> 2, wc = wid & 3;
  const int fr = lane & 15, fq = lane >> 4;

  // ds_read base addresses (LDS byte offsets; low 32 bits of generic ptr)
  const unsigned ldsb = (unsigned)(unsigned long long)&lds[0];
  const unsigned swzcol = ((unsigned)(fq * 16)) ^ ((unsigned)((fr & 7) << 4));
  const unsigned rcA = ldsb + (unsigned)((wr * 64 + fr) * 128) + swzcol;
  const unsigned rcB = ldsb + (unsigned)((wc * 32 + fr) * 128) + swzcol;

  f32x4 acc[8][4] = {};
  bf16x8 aFx[4][2], aFy[4][2], bF0[2][2], bF1[2][2], bF0n[2][2];

  // ---- prologue: tile0 (4 halves) + tile1 {A-mh0, B-nh1, A-mh1} ----
  stage_A_half(A, brow, 0, 0, lds + AOFF(0, 0), t);
  stage_B_half(B, bcol, 0, 1, lds + BOFF(0, 1), t);
  stage_A_half(A, brow, 0, 1, lds + AOFF(0, 1), t);
  stage_B_half(B, bcol, 0, 0, lds + BOFF(0, 0), t);
  stage_A_half(A, brow, BK, 0, lds + AOFF(1, 0), t);
  stage_B_half(B, bcol, BK, 1, lds + BOFF(1, 1), t);
  stage_A_half(A, brow, BK, 1, lds + AOFF(1, 1), t);
  VMW(6);  // tile0's 8 stage-loads landed
  __builtin_amdgcn_s_barrier();
  // q3(-1) role: read tile0's aFx + bF0 (12 outstanding entering the loop)
  rd_a(rcA + ((unsigned)AOFF(0, 0) << 1), aFx);
  rd_b(rcB + ((unsigned)BOFF(0, 0) << 1), bF0);

  for (int T = 0; T < NT; ++T) {
    const int b = T & 1;

    // -- q0: MFMA(mh0,nh0); issue bF1(T) reads; stage B-nh0(T+1)
    rd_b(rcB + ((unsigned)BOFF(b, 1) << 1), bF1);
    if (T + 1 < NT) stage_B_half(B, bcol, (T + 1) * BK, 0, lds + BOFF(b ^ 1, 0), t);
    LGKM(4);  // aFx + bF0 (issued last phase) drained; own 4 may pend
    MFMA16(aFx, bF0, 0, 0);
    __builtin_amdgcn_s_barrier();

    // -- q1: MFMA(mh0,nh1); issue aFy(T) reads; stage A-mh0(T+2)
    rd_a(rcA + ((unsigned)AOFF(b, 1) << 1), aFy);
    if (T + 2 < NT) stage_A_half(A, brow, (T + 2) * BK, 0, lds + AOFF(b, 0), t);
    LGKM(8);  // bF1 drained; own 8 may pend
    MFMA16(aFx, bF1, 0, 1);
    __builtin_amdgcn_s_barrier();

    // -- q2: MFMA(mh1,nh1); no reads; stage B-nh1(T+2); vmcnt once/tile
    if (T + 2 < NT) stage_B_half(B, bcol, (T + 2) * BK, 1, lds + BOFF(b, 1), t);
    LGKM(0);  // aFy drained (issued a full phase ago -> ~free)
    MFMA16(aFy, bF1, 1, 1);
    if (T < NT - 2)
      VMW(4);  // retires all tile-T+1 staging (outstanding = q1,q2 stages)
    else if (T == NT - 2)
      VMW(0);  // final drain
    __builtin_amdgcn_s_barrier();

    // -- q3: MFMA(mh1,nh0); issue aFx'+bF0n(T+1) reads; stage A-mh1(T+2)
    if (T + 1 < NT) {
      rd_a(rcA + ((unsigned)AOFF(b ^ 1, 0) << 1), aFx);
      rd_b(rcB + ((unsigned)BOFF(b ^ 1, 0) << 1), bF0n);
      if (T + 2 < NT) stage_A_half(A, brow, (T + 2) * BK, 1, lds + AOFF(b, 1), t);
      LGKM(12);  // nothing older outstanding; own 12 may pend
      MFMA16(aFy, bF0, 1, 0);  // uses OLD bF0 (pre-reload SSA values)
#pragma unroll
      for (int ni = 0; ni < 2; ++ni)
#pragma unroll
        for (int kk = 0; kk < 2; ++kk) bF0[ni][kk] = bF0n[ni][kk];
    } else {
      LGKM(0);
      MFMA16(aFy, bF0, 1, 0);
    }
    __builtin_amdgcn_s_barrier();
  }

  // ---- epilogue: scale/bias, C/D layout col=lane&15, row=(lane>>4)*4+j ----
#pragma unroll
  for (int n = 0; n < 4; ++n) {
    const int gc = bcol + wc * 64 + n * 16 + fr;
    const float s = scale[gc];
    const float bo = bias[gc];
#pragma unroll
    for (int m = 0; m < 8; ++m) {
      const int gr = brow + wr * 128 + m * 16 + fq * 4;
#pragma unroll
      for (int j = 0; j < 4; ++j)
        C[(size_t)(gr + j) * N_DIM + gc] = acc[m][n][j] * s + bo;
    }
  }
}

// ---------------- naive fallback (only if ws too small) ----------------

__global__ void naive_kernel(const float* __restrict__ x, const int* __restrict__ w,
                             const float* __restrict__ sc, const float* __restrict__ bi,
                             float* __restrict__ out) {
  size_t idx = (size_t)blockIdx.x * blockDim.x + threadIdx.x;
  int m = (int)(idx >> 12);
  int n = (int)(idx & 4095);
  const float* xr = x + (size_t)m * K_DIM;
  const int* wr = w + (size_t)n * K_DIM;
  float acc = 0.f;
  for (int k = 0; k < K_DIM; ++k) acc = fmaf(xr[k], (float)wr[k], acc);
  out[idx] = acc * sc[n] + bi[n];
}

extern "C" void kernel_launch(void* const* d_in, const int* in_sizes, int n_in,
                              void* d_out, int out_size, void* d_ws, size_t ws_size,
                              hipStream_t stream) {
  const float* x = (const float*)d_in[0];
  const int* w = (const int*)d_in[1];
  const float* scale = (const float*)d_in[2];
  const float* bias = (const float*)d_in[3];
  float* out = (float*)d_out;

  const long nx = (long)M_DIM * K_DIM;
  const long nw = (long)N_DIM * K_DIM;
  const size_t need = (size_t)nx * 2 + (size_t)nw * 2;  // 96 MiB

  if (ws_size >= need) {
    unsigned short* xb = (unsigned short*)d_ws;
    unsigned short* wb = xb + nx;
    cvt_fused_kernel<<<2048, 256, 0, stream>>>(x, w, xb, wb, nx, nw);
    gemm_bt_kernel<<<512, 512, 0, stream>>>(xb, wb, scale, bias, out);
  } else {
    naive_kernel<<<((long)M_DIM * N_DIM) / 256, 256, 0, stream>>>(x, w, scale, bias, out);
  }
}